// Round 2
// baseline (205.591 us; speedup 1.0000x reference)
//
#include <hip/hip_runtime.h>
#include <hip/hip_bf16.h>

typedef __attribute__((ext_vector_type(4))) float f32x4;
typedef __attribute__((ext_vector_type(8))) short bf16x8;

static __device__ __forceinline__ unsigned int pack_bf16_pair(float a, float b) {
  union { __hip_bfloat16 h; unsigned short u; } ca, cb;
  ca.h = __float2bfloat16(a);
  cb.h = __float2bfloat16(b);
  return (unsigned int)ca.u | ((unsigned int)cb.u << 16);
}

static __device__ __forceinline__ unsigned short bf16_bits(float a) {
  union { __hip_bfloat16 h; unsigned short u; } c;
  c.h = __float2bfloat16(a);
  return c.u;
}

// ---------------------------------------------------------------------------
// prep: K^T bf16 [80 o][64 c]; o = f(0..7) | g(8..15) | h(16..79)
// ---------------------------------------------------------------------------
__global__ void prep_kernel(const float* __restrict__ kf, const float* __restrict__ kg,
                            const float* __restrict__ kh, unsigned short* __restrict__ Kt)
{
  int idx = blockIdx.x * 256 + threadIdx.x;
  if (idx >= 80 * 64) return;
  int o = idx >> 6, c = idx & 63;
  float v = (o < 8) ? kf[c*8 + o] : (o < 16) ? kg[c*8 + (o - 8)] : kh[c*64 + (o - 16)];
  Kt[o*64 + c] = bf16_bits(v);
}

// ---------------------------------------------------------------------------
// proj: y = x(32768x64) * K^T(64x80) via MFMA 16x16x32. Block=256thr/4 waves,
// wave = 16 rows. Outputs: f_b[b][n][8] bf16, g_b[b][n][8] bf16,
// h_p[b][kt][c][128] bf16 with key-permuted inner index:
//   key local bits [kk(2)|a(1)|qd(2)|bb(2)]  ->  pi = kk*32 + qd*8 + a*4 + bb
// so that attn's PV B-frag (lane quad, slots j=0..7) is one contiguous 16B read.
// ---------------------------------------------------------------------------
__global__ __launch_bounds__(256) void proj_kernel(
    const float* __restrict__ x, const unsigned short* __restrict__ Kt,
    unsigned short* __restrict__ f_b, unsigned short* __restrict__ g_b,
    unsigned short* __restrict__ h_p)
{
  const int t = threadIdx.x, blk = blockIdx.x;
  const int w = t >> 6, lane = t & 63, l15 = lane & 15, quad = lane >> 4;
  const int Rbase = blk*64 + w*16;          // m-tile base row (global over 32768)
  const int R = Rbase + l15;                // this lane's A row

  // A-frags: x row -> bf16, k = kk*32 + quad*8 + j
  bf16x8 af[2];
  #pragma unroll
  for (int kk = 0; kk < 2; ++kk) {
    const float* xp = x + (long)R*64 + kk*32 + quad*8;
    float4 v0 = *(const float4*)xp;
    float4 v1 = *(const float4*)(xp + 4);
    union { unsigned int u[4]; bf16x8 v; } p;
    p.u[0] = pack_bf16_pair(v0.x, v0.y);
    p.u[1] = pack_bf16_pair(v0.z, v0.w);
    p.u[2] = pack_bf16_pair(v1.x, v1.y);
    p.u[3] = pack_bf16_pair(v1.z, v1.w);
    af[kk] = p.v;
  }

  f32x4 acc[5];
  #pragma unroll
  for (int nt = 0; nt < 5; ++nt) { f32x4 z = {}; acc[nt] = z; }

  #pragma unroll
  for (int nt = 0; nt < 5; ++nt)
    #pragma unroll
    for (int kk = 0; kk < 2; ++kk) {
      bf16x8 bfv = *(const bf16x8*)(Kt + (nt*16 + l15)*64 + kk*32 + quad*8);
      acc[nt] = __builtin_amdgcn_mfma_f32_16x16x32_bf16(af[kk], bfv, acc[nt], 0, 0, 0);
    }

  // C layout: col o = l15 (+16*nt), rows = Rbase + quad*4 + rr
  const int bt = Rbase >> 12;               // batch
  const int kt = (Rbase >> 7) & 31;         // key tile
  const int local = ((blk & 1) << 6) + (w << 4) + (quad << 2);  // key & 127 (bb=rr)
  const int pi = ((local >> 5) << 5) | (quad << 3) | (((local >> 4) & 1) << 2);

  // nt = 0: f / g outputs
  #pragma unroll
  for (int rr = 0; rr < 4; ++rr) {
    const int nq = (Rbase + quad*4 + rr) & 4095;
    unsigned short v = bf16_bits(acc[0][rr]);
    if (l15 < 8) f_b[((long)bt*4096 + nq)*8 + l15] = v;
    else         g_b[((long)bt*4096 + nq)*8 + (l15 - 8)] = v;
  }
  // nt 1..4: h channels, permuted store (4 keys -> 4 consecutive pi -> 8B)
  #pragma unroll
  for (int nt = 1; nt < 5; ++nt) {
    const int c = (nt - 1)*16 + l15;
    uint2 v;
    v.x = pack_bf16_pair(acc[nt][0], acc[nt][1]);
    v.y = pack_bf16_pair(acc[nt][2], acc[nt][3]);
    *(uint2*)(h_p + (((long)bt*32 + kt)*64 + c)*128 + pi) = v;
  }
}

// ---------------------------------------------------------------------------
// attn: zero-LDS flash attention. Block = 256 thr = 4 waves; wave owns 16 q.
// Per 128-key tile: S^T = f*g^T via 8 MFMAs (K=8 padded to 32; g-frag zeroed
// for quad>0 so f garbage multiplies 0). C-layout: lane l15 = q, keys at
// 16*t8 + 4*quad + rr  -> whole softmax row per lane (2 shfl_xor reduce).
// exp (no max: |s| < ~1), bf16-pack in-lane = PV A-frags under the permuted
// contraction order; PV B-frags are contiguous global 16B loads from h_p.
// ---------------------------------------------------------------------------
__global__ __launch_bounds__(256, 2) void attn_kernel(
    const float* __restrict__ x, const unsigned short* __restrict__ f_b,
    const unsigned short* __restrict__ g_b, const unsigned short* __restrict__ h_p,
    const float* __restrict__ gamma_p, float* __restrict__ out)
{
  const int t = threadIdx.x;
  const int w = t >> 6, lane = t & 63, l15 = lane & 15, quad = lane >> 4;
  const int qb = blockIdx.x, b = blockIdx.y;
  const int q0w = qb*64 + w*16;

  // g B-frag for S^T: n = q = l15, k = quad*8+j (only k<8 real -> quad>0 zeroed)
  bf16x8 gf;
  {
    bf16x8 gv = *(const bf16x8*)(g_b + ((long)b*4096 + q0w + l15)*8);
    bf16x8 z = {};
    gf = (quad == 0) ? gv : z;
  }

  f32x4 oacc[4];
  #pragma unroll
  for (int cf = 0; cf < 4; ++cf) { f32x4 z = {}; oacc[cf] = z; }
  float l_run = 0.f;

  const unsigned short* fb_b = f_b + (long)b*4096*8;
  const unsigned short* hp_b = h_p + (long)b*32*64*128;

  for (int kt = 0; kt < 32; ++kt) {
    // ---- S^T: 8 MFMAs over 128 keys ----
    const unsigned short* fkt = fb_b + kt*128*8;
    f32x4 sc[8];
    #pragma unroll
    for (int t8 = 0; t8 < 8; ++t8) {
      bf16x8 afv = *(const bf16x8*)(fkt + (t8*16 + l15)*8);
      f32x4 z = {};
      sc[t8] = __builtin_amdgcn_mfma_f32_16x16x32_bf16(afv, gf, z, 0, 0, 0);
    }

    // ---- exp + row sum (no max subtraction; scores are O(0.1)) ----
    float s0 = 0.f, s1 = 0.f, s2 = 0.f, s3 = 0.f;
    #pragma unroll
    for (int t8 = 0; t8 < 8; ++t8) {
      sc[t8][0] = __expf(sc[t8][0]);
      sc[t8][1] = __expf(sc[t8][1]);
      sc[t8][2] = __expf(sc[t8][2]);
      sc[t8][3] = __expf(sc[t8][3]);
      s0 += sc[t8][0]; s1 += sc[t8][1]; s2 += sc[t8][2]; s3 += sc[t8][3];
    }
    float ts = (s0 + s1) + (s2 + s3);
    ts += __shfl_xor(ts, 16);
    ts += __shfl_xor(ts, 32);
    l_run += ts;

    // ---- PV: A-frags from in-lane sc (permuted key order), B from global ----
    #pragma unroll
    for (int kk = 0; kk < 4; ++kk) {
      union { unsigned int u[4]; bf16x8 v; } ap;
      ap.u[0] = pack_bf16_pair(sc[2*kk][0],   sc[2*kk][1]);
      ap.u[1] = pack_bf16_pair(sc[2*kk][2],   sc[2*kk][3]);
      ap.u[2] = pack_bf16_pair(sc[2*kk+1][0], sc[2*kk+1][1]);
      ap.u[3] = pack_bf16_pair(sc[2*kk+1][2], sc[2*kk+1][3]);
      const unsigned short* hb = hp_b + (long)kt*64*128 + kk*32 + quad*8;
      #pragma unroll
      for (int cf = 0; cf < 4; ++cf) {
        bf16x8 bh = *(const bf16x8*)(hb + (cf*16 + l15)*128);
        oacc[cf] = __builtin_amdgcn_mfma_f32_16x16x32_bf16(ap.v, bh, oacc[cf], 0, 0, 0);
      }
    }
  }

  // ---- epilogue: divide by l, gamma*o + x ----
  float rinv = 1.0f / l_run;   // valid for q = l15 (same across quads)
  float rl[4];
  #pragma unroll
  for (int rr = 0; rr < 4; ++rr) rl[rr] = __shfl(rinv, quad*4 + rr);
  const float gma = gamma_p[0];

  #pragma unroll
  for (int cf = 0; cf < 4; ++cf)
    #pragma unroll
    for (int rr = 0; rr < 4; ++rr) {
      const long idx = ((long)b*4096 + q0w + quad*4 + rr)*64 + cf*16 + l15;
      out[idx] = fmaf(gma, oacc[cf][rr] * rl[rr], x[idx]);
    }
}

extern "C" void kernel_launch(void* const* d_in, const int* in_sizes, int n_in,
                              void* d_out, int out_size, void* d_ws, size_t ws_size,
                              hipStream_t stream) {
  const float* x  = (const float*)d_in[0];
  const float* kf = (const float*)d_in[1];
  const float* kg = (const float*)d_in[2];
  const float* kh = (const float*)d_in[3];
  const float* gamma = (const float*)d_in[4];
  float* out = (float*)d_out;

  char* ws = (char*)d_ws;
  unsigned short* h_p = (unsigned short*)ws;                       // 8*32*64*128*2 = 4 MB
  unsigned short* f_b = (unsigned short*)(ws + 4194304);           // 512 KB
  unsigned short* g_b = (unsigned short*)(ws + 4194304 + 524288);  // 512 KB
  unsigned short* Kt  = (unsigned short*)(ws + 5242880);           // 10 KB

  prep_kernel<<<20, 256, 0, stream>>>(kf, kg, kh, Kt);
  proj_kernel<<<512, 256, 0, stream>>>(x, Kt, f_b, g_b, h_p);
  attn_kernel<<<dim3(64, 8), 256, 0, stream>>>(x, f_b, g_b, h_p, gamma, out);
}

// Round 3
// 155.322 us; speedup vs baseline: 1.3236x; 1.3236x over previous
//
#include <hip/hip_runtime.h>
#include <hip/hip_bf16.h>

typedef __attribute__((ext_vector_type(4))) float f32x4;
typedef __attribute__((ext_vector_type(8))) short bf16x8;

// bf16 truncation pack: low ushort <- a, high ushort <- b (1x v_perm_b32).
// Trunc vs RNE costs one extra mantissa ulp (2^-8 rel) -- far inside margin.
static __device__ __forceinline__ unsigned int pack_trunc_f(float a, float b) {
  return __builtin_amdgcn_perm(__float_as_uint(b), __float_as_uint(a), 0x07060302);
}

// ---------------------------------------------------------------------------
// proj: y = x(32768x64) * K^T(64x80) via MFMA 16x16x32. Block=256thr/4 waves,
// wave = 16 rows. K^T (f|g|h packed, bf16, padded stride 72) built per-block
// in LDS (kills the separate prep launch). Outputs: f_b/g_b [b][n][8] bf16,
// h_p[b][kt][c][128] bf16 with key-permuted inner index:
//   local key bits [kk(2)|a(1)|qd(2)|bb(2)] -> pi = kk*32 + qd*8 + a*4 + bb
// so attn's PV B-frag (lane quad, slots j=0..7) is one contiguous 16B read.
// ---------------------------------------------------------------------------
__global__ __launch_bounds__(256) void proj_kernel(
    const float* __restrict__ x, const float* __restrict__ kf,
    const float* __restrict__ kg, const float* __restrict__ kh,
    unsigned short* __restrict__ f_b, unsigned short* __restrict__ g_b,
    unsigned short* __restrict__ h_p)
{
  __shared__ unsigned short Kt[80*72];   // rows 144B: 16B-aligned, conflict-min
  const int t = threadIdx.x, blk = blockIdx.x;

  #pragma unroll
  for (int r = 0; r < 20; ++r) {
    int idx = r*256 + t;                 // 5120 = 80x64
    int o = idx >> 6, c = idx & 63;
    float v = (o < 8) ? kf[c*8 + o] : (o < 16) ? kg[c*8 + (o-8)] : kh[c*64 + (o-16)];
    Kt[o*72 + c] = (unsigned short)(__float_as_uint(v) >> 16);
  }
  __syncthreads();

  const int w = t >> 6, lane = t & 63, l15 = lane & 15, quad = lane >> 4;
  const int Rbase = blk*64 + w*16;       // m-tile base row (global over 32768)
  const int R = Rbase + l15;

  // A-frags: x row -> bf16, k = kk*32 + quad*8 + j
  bf16x8 af[2];
  #pragma unroll
  for (int kk = 0; kk < 2; ++kk) {
    const float* xp = x + (long)R*64 + kk*32 + quad*8;
    float4 v0 = *(const float4*)xp;
    float4 v1 = *(const float4*)(xp + 4);
    union { unsigned int u[4]; bf16x8 v; } p;
    p.u[0] = pack_trunc_f(v0.x, v0.y);
    p.u[1] = pack_trunc_f(v0.z, v0.w);
    p.u[2] = pack_trunc_f(v1.x, v1.y);
    p.u[3] = pack_trunc_f(v1.z, v1.w);
    af[kk] = p.v;
  }

  f32x4 acc[5];
  #pragma unroll
  for (int nt = 0; nt < 5; ++nt) { f32x4 z = {}; acc[nt] = z; }

  #pragma unroll
  for (int nt = 0; nt < 5; ++nt)
    #pragma unroll
    for (int kk = 0; kk < 2; ++kk) {
      bf16x8 bfv = *(const bf16x8*)&Kt[(nt*16 + l15)*72 + kk*32 + quad*8];
      acc[nt] = __builtin_amdgcn_mfma_f32_16x16x32_bf16(af[kk], bfv, acc[nt], 0, 0, 0);
    }

  // C layout: col o = l15 (+16*nt), rows = Rbase + quad*4 + rr
  const int bt = Rbase >> 12;            // batch
  const int kt = (Rbase >> 7) & 31;      // key tile
  const int local = ((blk & 1) << 6) + (w << 4) + (quad << 2);  // key&127 (bb=rr)
  const int pi = ((local >> 5) << 5) | (quad << 3) | (((local >> 4) & 1) << 2);

  #pragma unroll
  for (int rr = 0; rr < 4; ++rr) {
    const int nq = (Rbase + quad*4 + rr) & 4095;
    unsigned short v = (unsigned short)(__float_as_uint(acc[0][rr]) >> 16);
    if (l15 < 8) f_b[((long)bt*4096 + nq)*8 + l15] = v;
    else         g_b[((long)bt*4096 + nq)*8 + (l15 - 8)] = v;
  }
  #pragma unroll
  for (int nt = 1; nt < 5; ++nt) {
    const int c = (nt - 1)*16 + l15;
    uint2 v;
    v.x = pack_trunc_f(acc[nt][0], acc[nt][1]);
    v.y = pack_trunc_f(acc[nt][2], acc[nt][3]);
    *(uint2*)(h_p + (((long)bt*32 + kt)*64 + c)*128 + pi) = v;
  }
}

// ---------------------------------------------------------------------------
// attn: flash attention, LDS-staged tiles + register prefetch across barrier.
// Block = 256 thr / 4 waves; wave owns 16 q; grid (64 qtiles, 8 batch).
// Per 128-key tile:
//   stage (regs->LDS, loaded last iter), barrier, prefetch kt+1 into regs,
//   S^T = f*g^T (8 MFMA, K=8 padded: g-frag zero for quad>0), exp (no max:
//   |s|<~1), sum via 2 shfl_xor, trunc-pack in-lane = PV A-frag under the
//   permuted key order, PV B-frags = ds_read_b128 from padded h tile.
// ---------------------------------------------------------------------------
__global__ __launch_bounds__(256) void attn_kernel(
    const float* __restrict__ x, const unsigned short* __restrict__ f_b,
    const unsigned short* __restrict__ g_b, const unsigned short* __restrict__ h_p,
    const float* __restrict__ gamma_p, float* __restrict__ out)
{
  __shared__ unsigned short fts[128*8];    // f tile: rows 16B (2 KB)
  __shared__ unsigned short hts[64*136];   // h tile: rows 272B padded (17.4 KB)

  const int t = threadIdx.x;
  const int w = t >> 6, lane = t & 63, l15 = lane & 15, quad = lane >> 4;
  const int qb = blockIdx.x, b = blockIdx.y;
  const int q0w = qb*64 + w*16;

  // g B-frag for S^T: n = q = l15, k = quad*8+j (k<8 real -> quad>0 zeroed)
  bf16x8 gf;
  {
    bf16x8 gv = *(const bf16x8*)(g_b + ((long)b*4096 + q0w + l15)*8);
    bf16x8 z = {};
    gf = (quad == 0) ? gv : z;
  }

  const unsigned short* fb_b = f_b + (long)b*4096*8;
  const unsigned short* hp_b = h_p + (long)b*32*64*128;

  const int srow = t >> 4;          // 0..15
  const int scol = (t & 15) * 8;    // ushort offset within 128-key row

  // prefetch tile 0 into registers
  uint4 hreg[4];
  uint4 freg = {};
  #pragma unroll
  for (int r = 0; r < 4; ++r)
    hreg[r] = *(const uint4*)(hp_b + (r*16 + srow)*128 + scol);
  if (t < 128) freg = *(const uint4*)(fb_b + t*8);

  f32x4 oacc[4];
  #pragma unroll
  for (int cf = 0; cf < 4; ++cf) { f32x4 z = {}; oacc[cf] = z; }
  float l_run = 0.f;

  for (int kt = 0; kt < 32; ++kt) {
    __syncthreads();                 // prev tile's LDS reads done
    #pragma unroll
    for (int r = 0; r < 4; ++r)
      *(uint4*)&hts[(r*16 + srow)*136 + scol] = hreg[r];
    if (t < 128) *(uint4*)&fts[t*8] = freg;
    __syncthreads();

    if (kt < 31) {                   // prefetch next tile; vmcnt wait lands
      const unsigned short* src = hp_b + (long)(kt+1)*8192;   // next ds_write
      #pragma unroll
      for (int r = 0; r < 4; ++r)
        hreg[r] = *(const uint4*)(src + (r*16 + srow)*128 + scol);
      if (t < 128) freg = *(const uint4*)(fb_b + (kt+1)*1024 + t*8);
    }

    // ---- S^T: 8 MFMAs over 128 keys (A = f rows, broadcast across quads) ----
    f32x4 sc[8];
    #pragma unroll
    for (int t8 = 0; t8 < 8; ++t8) {
      bf16x8 afv = *(const bf16x8*)&fts[(t8*16 + l15)*8];
      f32x4 z = {};
      sc[t8] = __builtin_amdgcn_mfma_f32_16x16x32_bf16(afv, gf, z, 0, 0, 0);
    }

    // ---- exp + row sum (scores O(0.1): no max subtraction needed) ----
    float s0 = 0.f, s1 = 0.f, s2 = 0.f, s3 = 0.f;
    #pragma unroll
    for (int t8 = 0; t8 < 8; ++t8) {
      sc[t8][0] = __expf(sc[t8][0]);
      sc[t8][1] = __expf(sc[t8][1]);
      sc[t8][2] = __expf(sc[t8][2]);
      sc[t8][3] = __expf(sc[t8][3]);
      s0 += sc[t8][0]; s1 += sc[t8][1]; s2 += sc[t8][2]; s3 += sc[t8][3];
    }
    float ts = (s0 + s1) + (s2 + s3);
    ts += __shfl_xor(ts, 16);
    ts += __shfl_xor(ts, 32);
    l_run += ts;

    // ---- PV: A from in-lane sc (permuted key order), B from padded LDS ----
    #pragma unroll
    for (int kk = 0; kk < 4; ++kk) {
      union { unsigned int u[4]; bf16x8 v; } ap;
      ap.u[0] = pack_trunc_f(sc[2*kk][0],   sc[2*kk][1]);
      ap.u[1] = pack_trunc_f(sc[2*kk][2],   sc[2*kk][3]);
      ap.u[2] = pack_trunc_f(sc[2*kk+1][0], sc[2*kk+1][1]);
      ap.u[3] = pack_trunc_f(sc[2*kk+1][2], sc[2*kk+1][3]);
      #pragma unroll
      for (int cf = 0; cf < 4; ++cf) {
        bf16x8 bh = *(const bf16x8*)&hts[(cf*16 + l15)*136 + kk*32 + quad*8];
        oacc[cf] = __builtin_amdgcn_mfma_f32_16x16x32_bf16(ap.v, bh, oacc[cf], 0, 0, 0);
      }
    }
  }

  // ---- epilogue: divide by l, gamma*o + x ----
  float rinv = 1.0f / l_run;          // valid for q = l15 (all quads reduced)
  float rl[4];
  #pragma unroll
  for (int rr = 0; rr < 4; ++rr) rl[rr] = __shfl(rinv, quad*4 + rr);
  const float gma = gamma_p[0];

  #pragma unroll
  for (int cf = 0; cf < 4; ++cf)
    #pragma unroll
    for (int rr = 0; rr < 4; ++rr) {
      const long idx = ((long)b*4096 + q0w + quad*4 + rr)*64 + cf*16 + l15;
      out[idx] = fmaf(gma, oacc[cf][rr] * rl[rr], x[idx]);
    }
}

extern "C" void kernel_launch(void* const* d_in, const int* in_sizes, int n_in,
                              void* d_out, int out_size, void* d_ws, size_t ws_size,
                              hipStream_t stream) {
  const float* x  = (const float*)d_in[0];
  const float* kf = (const float*)d_in[1];
  const float* kg = (const float*)d_in[2];
  const float* kh = (const float*)d_in[3];
  const float* gamma = (const float*)d_in[4];
  float* out = (float*)d_out;

  char* ws = (char*)d_ws;
  unsigned short* h_p = (unsigned short*)ws;                       // 4 MB
  unsigned short* f_b = (unsigned short*)(ws + 4194304);           // 512 KB
  unsigned short* g_b = (unsigned short*)(ws + 4194304 + 524288);  // 512 KB

  proj_kernel<<<512, 256, 0, stream>>>(x, kf, kg, kh, f_b, g_b, h_p);
  attn_kernel<<<dim3(64, 8), 256, 0, stream>>>(x, f_b, g_b, h_p, gamma, out);
}

// Round 4
// 117.197 us; speedup vs baseline: 1.7542x; 1.3253x over previous
//
#include <hip/hip_runtime.h>
#include <hip/hip_bf16.h>

typedef __attribute__((ext_vector_type(4)))  float f32x4;
typedef __attribute__((ext_vector_type(16))) float f32x16;
typedef __attribute__((ext_vector_type(8)))  short bf16x8;

#define LOG2E 1.44269504088896340736f

// bf16 truncation pack: low ushort <- a, high ushort <- b (1x v_perm_b32).
static __device__ __forceinline__ unsigned int pack_trunc_f(float a, float b) {
  return __builtin_amdgcn_perm(__float_as_uint(b), __float_as_uint(a), 0x07060302);
}

// async global->LDS, 16B per lane: dest = (wave-uniform) l + lane*16
typedef const __attribute__((address_space(1))) unsigned int gu32;
typedef __attribute__((address_space(3))) unsigned int lu32;
static __device__ __forceinline__ void gload_lds16(const void* g, void* l) {
  __builtin_amdgcn_global_load_lds((gu32*)g, (lu32*)l, 16, 0, 0);
}

// ---------------------------------------------------------------------------
// proj: y = x(32768x64) * K^T(64x80) via MFMA 16x16x32. Block=256thr/4 waves.
// g-columns pre-scaled by log2(e) so attn can use exp2 directly.
// h stored per 128-key tile as [c][136] bf16 (8-slot pad, garbage) with keys
// at PERMUTED position kpos = bitswap2<->3(key&127), which makes attn's
// S^T C-layout == PV A-layout with contiguous B-frags.
// ---------------------------------------------------------------------------
__global__ __launch_bounds__(256) void proj_kernel(
    const float* __restrict__ x, const float* __restrict__ kf,
    const float* __restrict__ kg, const float* __restrict__ kh,
    unsigned short* __restrict__ f_b, unsigned short* __restrict__ g_b,
    unsigned short* __restrict__ h_p)
{
  __shared__ unsigned short Kt[80*72];
  const int t = threadIdx.x, blk = blockIdx.x;

  #pragma unroll
  for (int r = 0; r < 20; ++r) {
    int idx = r*256 + t;                 // 5120 = 80x64
    int o = idx >> 6, c = idx & 63;
    float v = (o < 8) ? kf[c*8 + o]
            : (o < 16) ? kg[c*8 + (o-8)] * LOG2E
            : kh[c*64 + (o-16)];
    Kt[o*72 + c] = (unsigned short)(__float_as_uint(v) >> 16);
  }
  __syncthreads();

  const int w = t >> 6, lane = t & 63, l15 = lane & 15, quad = lane >> 4;
  const int Rbase = blk*64 + w*16;
  const int R = Rbase + l15;

  bf16x8 af[2];
  #pragma unroll
  for (int kk = 0; kk < 2; ++kk) {
    const float* xp = x + (long)R*64 + kk*32 + quad*8;
    float4 v0 = *(const float4*)xp;
    float4 v1 = *(const float4*)(xp + 4);
    union { unsigned int u[4]; bf16x8 v; } p;
    p.u[0] = pack_trunc_f(v0.x, v0.y);
    p.u[1] = pack_trunc_f(v0.z, v0.w);
    p.u[2] = pack_trunc_f(v1.x, v1.y);
    p.u[3] = pack_trunc_f(v1.z, v1.w);
    af[kk] = p.v;
  }

  f32x4 acc[5];
  #pragma unroll
  for (int nt = 0; nt < 5; ++nt) { f32x4 z = {}; acc[nt] = z; }

  #pragma unroll
  for (int nt = 0; nt < 5; ++nt)
    #pragma unroll
    for (int kk = 0; kk < 2; ++kk) {
      bf16x8 bfv = *(const bf16x8*)&Kt[(nt*16 + l15)*72 + kk*32 + quad*8];
      acc[nt] = __builtin_amdgcn_mfma_f32_16x16x32_bf16(af[kk], bfv, acc[nt], 0, 0, 0);
    }

  const int bt = Rbase >> 12;
  const int kt = (Rbase >> 7) & 31;
  // in-tile key base for this wave's C rows; rows = base + quad*4 + rr
  const int base = ((blk & 1) << 6) + (w << 4);
  // permuted store position: swap bits 2<->3 of (base + 4*quad + rr)
  const int pi = base + ((quad & 1) << 3) + (((quad >> 1) & 1) << 2);

  #pragma unroll
  for (int rr = 0; rr < 4; ++rr) {
    const int nq = (Rbase + quad*4 + rr) & 4095;
    unsigned short v = (unsigned short)(__float_as_uint(acc[0][rr]) >> 16);
    if (l15 < 8) f_b[((long)bt*4096 + nq)*8 + l15] = v;
    else         g_b[((long)bt*4096 + nq)*8 + (l15 - 8)] = v;
  }
  #pragma unroll
  for (int nt = 1; nt < 5; ++nt) {
    const int c = (nt - 1)*16 + l15;
    uint2 v;
    v.x = pack_trunc_f(acc[nt][0], acc[nt][1]);
    v.y = pack_trunc_f(acc[nt][2], acc[nt][3]);
    *(uint2*)(h_p + ((long)(bt*32 + kt)*64 + c)*136 + pi) = v;
  }
}

// ---------------------------------------------------------------------------
// attn: split-K flash attention (no-max softmax; |s| << 1 by construction).
// Grid (64 qtiles, 8 batch, 4 splits); block = 128 thr = 2 waves; wave = 32 q.
// Per 128-key tile (8 tiles per split):
//   stage via global_load_lds (h 17 KB pre-padded + f 2 KB), barrier-drain;
//   per 32-key sub-tile mt: S^T = f*g^T (1x mfma 32x32x16, K=8 padded:
//   g zeroed on lane-half a=1), exp2 the 16 C-regs, trunc-pack pairs ->
//   PV A-frags (C-reg order == A-slot order thanks to the bit-swapped h
//   storage), 2 PV steps x 2 n-tiles of mfma 32x32x16 from LDS B-frags.
// Partials: o (bf16) and l (f32) per split -> combine kernel.
// ---------------------------------------------------------------------------
__global__ __launch_bounds__(128, 4) void attn_kernel(
    const unsigned short* __restrict__ f_b, const unsigned short* __restrict__ g_b,
    const unsigned short* __restrict__ h_p, unsigned short* __restrict__ po,
    float* __restrict__ pl)
{
  __shared__ unsigned short hts[64*136];   // [c][kpos], straight copy of h_p tile
  __shared__ unsigned short fts[128*8];    // [key][ch]

  const int t = threadIdx.x;
  const int w = t >> 6, lane = t & 63, l31 = lane & 31, a = lane >> 5;
  const int qb = blockIdx.x, b = blockIdx.y, sp = blockIdx.z;
  const int q0w = qb*64 + w*32;

  // g B-frag: n = q = l31, k = a*8+j ; real channels only at a=0
  bf16x8 gf;
  {
    bf16x8 gv = *(const bf16x8*)(g_b + ((long)b*4096 + q0w + l31)*8);
    bf16x8 z = {};
    gf = (a == 0) ? gv : z;
  }

  f32x16 oacc[2];
  { f32x16 z = {}; oacc[0] = z; oacc[1] = z; }
  float l_run = 0.f;

  const char* hp_b = (const char*)h_p + (long)b*32*17408;
  const char* fb_b = (const char*)f_b + (long)b*4096*16;

  for (int ktl = 0; ktl < 8; ++ktl) {
    const int kt = sp*8 + ktl;
    __syncthreads();                       // prev tile's LDS reads done
    const char* hsrc = hp_b + (long)kt*17408;
    const char* fsrc = fb_b + (long)kt*2048;
    if (w == 0) {
      #pragma unroll
      for (int i = 0; i < 9; ++i)
        gload_lds16(hsrc + i*1024 + lane*16, (char*)hts + i*1024);
      gload_lds16(fsrc + lane*16, (char*)fts);
    } else {
      #pragma unroll
      for (int i = 9; i < 17; ++i)
        gload_lds16(hsrc + i*1024 + lane*16, (char*)hts + i*1024);
      gload_lds16(fsrc + 1024 + lane*16, (char*)fts + 1024);
    }
    __syncthreads();                       // vmcnt drain: tiles visible

    #pragma unroll
    for (int mt = 0; mt < 4; ++mt) {
      // S^T sub-tile: keys mt*32..mt*32+31 (storage order) x 32 queries
      bf16x8 afv = *(const bf16x8*)&fts[(mt*32 + l31)*8];   // both halves same addr
      f32x16 zz = {};
      f32x16 sc = __builtin_amdgcn_mfma_f32_32x32x16_bf16(afv, gf, zz, 0, 0, 0);

      float e[16];
      #pragma unroll
      for (int r = 0; r < 16; ++r) {
        e[r] = exp2f(sc[r]);               // g pre-scaled by log2e
        l_run += e[r];
      }

      #pragma unroll
      for (int half = 0; half < 2; ++half) {
        const int s = mt*2 + half;         // PV K-step: contraction k in [16s,16s+16)
        union { unsigned int u[4]; bf16x8 v; } ap;
        ap.u[0] = pack_trunc_f(e[half*8+0], e[half*8+1]);
        ap.u[1] = pack_trunc_f(e[half*8+2], e[half*8+3]);
        ap.u[2] = pack_trunc_f(e[half*8+4], e[half*8+5]);
        ap.u[3] = pack_trunc_f(e[half*8+6], e[half*8+7]);
        #pragma unroll
        for (int nt = 0; nt < 2; ++nt) {
          bf16x8 bh = *(const bf16x8*)&hts[(nt*32 + l31)*136 + s*16 + a*8];
          oacc[nt] = __builtin_amdgcn_mfma_f32_32x32x16_bf16(ap.v, bh, oacc[nt], 0, 0, 0);
        }
      }
    }
  }

  // partial l: this lane covers 64 keys/tile for query l31; other half has rest
  l_run += __shfl_xor(l_run, 32);
  const long sb = (long)sp*8 + b;
  if (lane < 32) pl[(sb << 12) + q0w + l31] = l_run;

  // partial o: C-layout col = c = nt*32+l31, row q = q0w + (r&3)+8*(r>>2)+4a
  unsigned short* pob = po + ((sb << 12) + q0w)*64;
  #pragma unroll
  for (int nt = 0; nt < 2; ++nt)
    #pragma unroll
    for (int r = 0; r < 16; ++r) {
      const int q = (r & 3) + 8*(r >> 2) + 4*a;
      pob[(long)q*64 + nt*32 + l31] =
          (unsigned short)(__float_as_uint(oacc[nt][r]) >> 16);
    }
}

// ---------------------------------------------------------------------------
// combine: out = gamma * (sum_s po) / (sum_s pl) + x.  One thread = 8 channels.
// ---------------------------------------------------------------------------
__global__ __launch_bounds__(256) void combine_kernel(
    const float* __restrict__ x, const unsigned short* __restrict__ po,
    const float* __restrict__ pl, const float* __restrict__ gamma_p,
    float* __restrict__ out)
{
  const long tid = (long)blockIdx.x*256 + threadIdx.x;   // 262144
  const long bn = tid >> 3;
  const int c0 = (int)(tid & 7)*8;

  float l = 0.f;
  float o[8];
  #pragma unroll
  for (int i = 0; i < 8; ++i) o[i] = 0.f;
  #pragma unroll
  for (int s = 0; s < 4; ++s) {
    l += pl[(long)s*32768 + bn];
    uint4 v = *(const uint4*)(po + ((long)s*32768 + bn)*64 + c0);
    const unsigned short* pv = (const unsigned short*)&v;
    #pragma unroll
    for (int i = 0; i < 8; ++i)
      o[i] += __uint_as_float((unsigned int)pv[i] << 16);
  }
  const float scale = gamma_p[0] / l;
  const float* xp = x + bn*64 + c0;
  float4 x0 = *(const float4*)xp;
  float4 x1 = *(const float4*)(xp + 4);
  float4 r0, r1;
  r0.x = fmaf(scale, o[0], x0.x);
  r0.y = fmaf(scale, o[1], x0.y);
  r0.z = fmaf(scale, o[2], x0.z);
  r0.w = fmaf(scale, o[3], x0.w);
  r1.x = fmaf(scale, o[4], x1.x);
  r1.y = fmaf(scale, o[5], x1.y);
  r1.z = fmaf(scale, o[6], x1.z);
  r1.w = fmaf(scale, o[7], x1.w);
  float* op = out + bn*64 + c0;
  *(float4*)op = r0;
  *(float4*)(op + 4) = r1;
}

extern "C" void kernel_launch(void* const* d_in, const int* in_sizes, int n_in,
                              void* d_out, int out_size, void* d_ws, size_t ws_size,
                              hipStream_t stream) {
  const float* x  = (const float*)d_in[0];
  const float* kf = (const float*)d_in[1];
  const float* kg = (const float*)d_in[2];
  const float* kh = (const float*)d_in[3];
  const float* gamma = (const float*)d_in[4];
  float* out = (float*)d_out;

  char* ws = (char*)d_ws;
  unsigned short* h_p = (unsigned short*)ws;                  // 8*32*64*136*2 = 4,456,448
  unsigned short* f_b = (unsigned short*)(ws + 4456448);      // 524,288
  unsigned short* g_b = (unsigned short*)(ws + 4980736);      // 524,288
  unsigned short* po  = (unsigned short*)(ws + 5505024);      // 4*8*4096*64*2 = 16,777,216
  float*          pl  = (float*)(ws + 22282240);              // 4*8*4096*4 = 524,288
                                                              // total 22,806,528 B

  proj_kernel<<<512, 256, 0, stream>>>(x, kf, kg, kh, f_b, g_b, h_p);
  attn_kernel<<<dim3(64, 8, 4), 128, 0, stream>>>(f_b, g_b, h_p, po, pl);
  combine_kernel<<<1024, 256, 0, stream>>>(x, po, pl, gamma, out);
}

// Round 5
// 104.519 us; speedup vs baseline: 1.9670x; 1.1213x over previous
//
#include <hip/hip_runtime.h>
#include <hip/hip_bf16.h>

typedef __attribute__((ext_vector_type(4)))  float f32x4;
typedef __attribute__((ext_vector_type(16))) float f32x16;
typedef __attribute__((ext_vector_type(8)))  short bf16x8;

#define LOG2E 1.44269504088896340736f

// native v_exp_f32 (1 instr, ~1 ulp). exp2f without fast-math lowers to the
// precise OCML sequence (~30 cyc) -- that was 85% of round-4's VALU time.
#if __has_builtin(__builtin_amdgcn_exp2f)
static __device__ __forceinline__ float exp2_native(float x) {
  return __builtin_amdgcn_exp2f(x);
}
#else
extern "C" __device__ float __ocml_native_exp2_f32(float);
static __device__ __forceinline__ float exp2_native(float x) {
  return __ocml_native_exp2_f32(x);
}
#endif

// bf16 truncation pack: low ushort <- a, high ushort <- b (1x v_perm_b32).
static __device__ __forceinline__ unsigned int pack_trunc_f(float a, float b) {
  return __builtin_amdgcn_perm(__float_as_uint(b), __float_as_uint(a), 0x07060302);
}

// async global->LDS, 16B per lane: dest = (wave-uniform) l + lane*16
typedef const __attribute__((address_space(1))) unsigned int gu32;
typedef __attribute__((address_space(3))) unsigned int lu32;
static __device__ __forceinline__ void gload_lds16(const void* g, void* l) {
  __builtin_amdgcn_global_load_lds((gu32*)g, (lu32*)l, 16, 0, 0);
}

// ---------------------------------------------------------------------------
// proj: y = x(32768x64) * K^T(64x80) via MFMA 16x16x32. Block=256thr/4 waves.
// g-columns pre-scaled by log2(e) so attn can use native exp2 directly.
// h stored per 128-key tile as [c][136] bf16 (8-slot pad, garbage) with keys
// at PERMUTED position kpos = bitswap2<->3(key&127), which makes attn's
// S^T C-layout == PV A-layout with contiguous B-frags.
// ---------------------------------------------------------------------------
__global__ __launch_bounds__(256) void proj_kernel(
    const float* __restrict__ x, const float* __restrict__ kf,
    const float* __restrict__ kg, const float* __restrict__ kh,
    unsigned short* __restrict__ f_b, unsigned short* __restrict__ g_b,
    unsigned short* __restrict__ h_p)
{
  __shared__ unsigned short Kt[80*72];
  const int t = threadIdx.x, blk = blockIdx.x;

  #pragma unroll
  for (int r = 0; r < 20; ++r) {
    int idx = r*256 + t;                 // 5120 = 80x64
    int o = idx >> 6, c = idx & 63;
    float v = (o < 8) ? kf[c*8 + o]
            : (o < 16) ? kg[c*8 + (o-8)] * LOG2E
            : kh[c*64 + (o-16)];
    Kt[o*72 + c] = (unsigned short)(__float_as_uint(v) >> 16);
  }
  __syncthreads();

  const int w = t >> 6, lane = t & 63, l15 = lane & 15, quad = lane >> 4;
  const int Rbase = blk*64 + w*16;
  const int R = Rbase + l15;

  bf16x8 af[2];
  #pragma unroll
  for (int kk = 0; kk < 2; ++kk) {
    const float* xp = x + (long)R*64 + kk*32 + quad*8;
    float4 v0 = *(const float4*)xp;
    float4 v1 = *(const float4*)(xp + 4);
    union { unsigned int u[4]; bf16x8 v; } p;
    p.u[0] = pack_trunc_f(v0.x, v0.y);
    p.u[1] = pack_trunc_f(v0.z, v0.w);
    p.u[2] = pack_trunc_f(v1.x, v1.y);
    p.u[3] = pack_trunc_f(v1.z, v1.w);
    af[kk] = p.v;
  }

  f32x4 acc[5];
  #pragma unroll
  for (int nt = 0; nt < 5; ++nt) { f32x4 z = {}; acc[nt] = z; }

  #pragma unroll
  for (int nt = 0; nt < 5; ++nt)
    #pragma unroll
    for (int kk = 0; kk < 2; ++kk) {
      bf16x8 bfv = *(const bf16x8*)&Kt[(nt*16 + l15)*72 + kk*32 + quad*8];
      acc[nt] = __builtin_amdgcn_mfma_f32_16x16x32_bf16(af[kk], bfv, acc[nt], 0, 0, 0);
    }

  const int bt = Rbase >> 12;
  const int kt = (Rbase >> 7) & 31;
  // in-tile key base for this wave's C rows; rows = base + quad*4 + rr
  const int base = ((blk & 1) << 6) + (w << 4);
  // permuted store position: swap bits 2<->3 of (base + 4*quad + rr)
  const int pi = base + ((quad & 1) << 3) + (((quad >> 1) & 1) << 2);

  #pragma unroll
  for (int rr = 0; rr < 4; ++rr) {
    const int nq = (Rbase + quad*4 + rr) & 4095;
    unsigned short v = (unsigned short)(__float_as_uint(acc[0][rr]) >> 16);
    if (l15 < 8) f_b[((long)bt*4096 + nq)*8 + l15] = v;
    else         g_b[((long)bt*4096 + nq)*8 + (l15 - 8)] = v;
  }
  #pragma unroll
  for (int nt = 1; nt < 5; ++nt) {
    const int c = (nt - 1)*16 + l15;
    uint2 v;
    v.x = pack_trunc_f(acc[nt][0], acc[nt][1]);
    v.y = pack_trunc_f(acc[nt][2], acc[nt][3]);
    *(uint2*)(h_p + ((long)(bt*32 + kt)*64 + c)*136 + pi) = v;
  }
}

// ---------------------------------------------------------------------------
// attn: split-K flash attention (no-max softmax; |s| << 1 by construction).
// Grid (64 qtiles, 8 batch, 4 splits); block = 128 thr = 2 waves; wave = 32 q.
// Per 128-key tile (8 tiles per split):
//   stage via global_load_lds (h 17 KB pre-padded + f 2 KB), barrier-drain;
//   per 32-key sub-tile mt: S^T = f*g^T (1x mfma 32x32x16, K=8 padded:
//   g zeroed on lane-half a=1), native exp2 the 16 C-regs, trunc-pack pairs
//   -> PV A-frags (C-reg order == A-slot order thanks to the bit-swapped h
//   storage), 2 PV steps x 2 n-tiles of mfma 32x32x16 from LDS B-frags.
// Partials: o (bf16) and l (f32) per split -> combine kernel.
// ---------------------------------------------------------------------------
__global__ __launch_bounds__(128, 4) void attn_kernel(
    const unsigned short* __restrict__ f_b, const unsigned short* __restrict__ g_b,
    const unsigned short* __restrict__ h_p, unsigned short* __restrict__ po,
    float* __restrict__ pl)
{
  __shared__ unsigned short hts[64*136];   // [c][kpos], straight copy of h_p tile
  __shared__ unsigned short fts[128*8];    // [key][ch]

  const int t = threadIdx.x;
  const int w = t >> 6, lane = t & 63, l31 = lane & 31, a = lane >> 5;
  const int qb = blockIdx.x, b = blockIdx.y, sp = blockIdx.z;
  const int q0w = qb*64 + w*32;

  // g B-frag: n = q = l31, k = a*8+j ; real channels only at a=0
  bf16x8 gf;
  {
    bf16x8 gv = *(const bf16x8*)(g_b + ((long)b*4096 + q0w + l31)*8);
    bf16x8 z = {};
    gf = (a == 0) ? gv : z;
  }

  f32x16 oacc[2];
  { f32x16 z = {}; oacc[0] = z; oacc[1] = z; }
  float l_run = 0.f;

  const char* hp_b = (const char*)h_p + (long)b*32*17408;
  const char* fb_b = (const char*)f_b + (long)b*4096*16;

  for (int ktl = 0; ktl < 8; ++ktl) {
    const int kt = sp*8 + ktl;
    __syncthreads();                       // prev tile's LDS reads done
    const char* hsrc = hp_b + (long)kt*17408;
    const char* fsrc = fb_b + (long)kt*2048;
    if (w == 0) {
      #pragma unroll
      for (int i = 0; i < 9; ++i)
        gload_lds16(hsrc + i*1024 + lane*16, (char*)hts + i*1024);
      gload_lds16(fsrc + lane*16, (char*)fts);
    } else {
      #pragma unroll
      for (int i = 9; i < 17; ++i)
        gload_lds16(hsrc + i*1024 + lane*16, (char*)hts + i*1024);
      gload_lds16(fsrc + 1024 + lane*16, (char*)fts + 1024);
    }
    __syncthreads();                       // vmcnt drain: tiles visible

    #pragma unroll
    for (int mt = 0; mt < 4; ++mt) {
      // S^T sub-tile: keys mt*32..mt*32+31 (storage order) x 32 queries
      bf16x8 afv = *(const bf16x8*)&fts[(mt*32 + l31)*8];   // both halves same addr
      f32x16 zz = {};
      f32x16 sc = __builtin_amdgcn_mfma_f32_32x32x16_bf16(afv, gf, zz, 0, 0, 0);

      float e[16];
      #pragma unroll
      for (int r = 0; r < 16; ++r) {
        e[r] = exp2_native(sc[r]);         // g pre-scaled by log2e
        l_run += e[r];
      }

      #pragma unroll
      for (int half = 0; half < 2; ++half) {
        const int s = mt*2 + half;         // PV K-step: contraction k in [16s,16s+16)
        union { unsigned int u[4]; bf16x8 v; } ap;
        ap.u[0] = pack_trunc_f(e[half*8+0], e[half*8+1]);
        ap.u[1] = pack_trunc_f(e[half*8+2], e[half*8+3]);
        ap.u[2] = pack_trunc_f(e[half*8+4], e[half*8+5]);
        ap.u[3] = pack_trunc_f(e[half*8+6], e[half*8+7]);
        #pragma unroll
        for (int nt = 0; nt < 2; ++nt) {
          bf16x8 bh = *(const bf16x8*)&hts[(nt*32 + l31)*136 + s*16 + a*8];
          oacc[nt] = __builtin_amdgcn_mfma_f32_32x32x16_bf16(ap.v, bh, oacc[nt], 0, 0, 0);
        }
      }
    }
  }

  // partial l: this lane covers 64 keys/tile for query l31; other half has rest
  l_run += __shfl_xor(l_run, 32);
  const long sb = (long)sp*8 + b;
  if (lane < 32) pl[(sb << 12) + q0w + l31] = l_run;

  // partial o: C-layout col = c = nt*32+l31, row q = q0w + (r&3)+8*(r>>2)+4a
  unsigned short* pob = po + ((sb << 12) + q0w)*64;
  #pragma unroll
  for (int nt = 0; nt < 2; ++nt)
    #pragma unroll
    for (int r = 0; r < 16; ++r) {
      const int q = (r & 3) + 8*(r >> 2) + 4*a;
      pob[(long)q*64 + nt*32 + l31] =
          (unsigned short)(__float_as_uint(oacc[nt][r]) >> 16);
    }
}

// ---------------------------------------------------------------------------
// combine: out = gamma * (sum_s po) / (sum_s pl) + x.  One thread = 8 channels.
// ---------------------------------------------------------------------------
__global__ __launch_bounds__(256) void combine_kernel(
    const float* __restrict__ x, const unsigned short* __restrict__ po,
    const float* __restrict__ pl, const float* __restrict__ gamma_p,
    float* __restrict__ out)
{
  const long tid = (long)blockIdx.x*256 + threadIdx.x;   // 262144
  const long bn = tid >> 3;
  const int c0 = (int)(tid & 7)*8;

  float l = 0.f;
  float o[8];
  #pragma unroll
  for (int i = 0; i < 8; ++i) o[i] = 0.f;
  #pragma unroll
  for (int s = 0; s < 4; ++s) {
    l += pl[(long)s*32768 + bn];
    uint4 v = *(const uint4*)(po + ((long)s*32768 + bn)*64 + c0);
    const unsigned short* pv = (const unsigned short*)&v;
    #pragma unroll
    for (int i = 0; i < 8; ++i)
      o[i] += __uint_as_float((unsigned int)pv[i] << 16);
  }
  const float scale = gamma_p[0] / l;
  const float* xp = x + bn*64 + c0;
  float4 x0 = *(const float4*)xp;
  float4 x1 = *(const float4*)(xp + 4);
  float4 r0, r1;
  r0.x = fmaf(scale, o[0], x0.x);
  r0.y = fmaf(scale, o[1], x0.y);
  r0.z = fmaf(scale, o[2], x0.z);
  r0.w = fmaf(scale, o[3], x0.w);
  r1.x = fmaf(scale, o[4], x1.x);
  r1.y = fmaf(scale, o[5], x1.y);
  r1.z = fmaf(scale, o[6], x1.z);
  r1.w = fmaf(scale, o[7], x1.w);
  float* op = out + bn*64 + c0;
  *(float4*)op = r0;
  *(float4*)(op + 4) = r1;
}

extern "C" void kernel_launch(void* const* d_in, const int* in_sizes, int n_in,
                              void* d_out, int out_size, void* d_ws, size_t ws_size,
                              hipStream_t stream) {
  const float* x  = (const float*)d_in[0];
  const float* kf = (const float*)d_in[1];
  const float* kg = (const float*)d_in[2];
  const float* kh = (const float*)d_in[3];
  const float* gamma = (const float*)d_in[4];
  float* out = (float*)d_out;

  char* ws = (char*)d_ws;
  unsigned short* h_p = (unsigned short*)ws;                  // 8*32*64*136*2 = 4,456,448
  unsigned short* f_b = (unsigned short*)(ws + 4456448);      // 524,288
  unsigned short* g_b = (unsigned short*)(ws + 4980736);      // 524,288
  unsigned short* po  = (unsigned short*)(ws + 5505024);      // 4*8*4096*64*2 = 16,777,216
  float*          pl  = (float*)(ws + 22282240);              // 4*8*4096*4 = 524,288
                                                              // total 22,806,528 B

  proj_kernel<<<512, 256, 0, stream>>>(x, kf, kg, kh, f_b, g_b, h_p);
  attn_kernel<<<dim3(64, 8, 4), 128, 0, stream>>>(f_b, g_b, h_p, po, pl);
  combine_kernel<<<1024, 256, 0, stream>>>(x, po, pl, gamma, out);
}

// Round 6
// 102.693 us; speedup vs baseline: 2.0020x; 1.0178x over previous
//
#include <hip/hip_runtime.h>
#include <hip/hip_bf16.h>

typedef __attribute__((ext_vector_type(4)))  float f32x4;
typedef __attribute__((ext_vector_type(16))) float f32x16;
typedef __attribute__((ext_vector_type(8)))  short bf16x8;

#define LOG2E 1.44269504088896340736f

// native v_exp_f32 (1 instr, ~1 ulp); plain exp2f lowers to precise OCML (~30 cyc).
#if __has_builtin(__builtin_amdgcn_exp2f)
static __device__ __forceinline__ float exp2_native(float x) {
  return __builtin_amdgcn_exp2f(x);
}
#else
extern "C" __device__ float __ocml_native_exp2_f32(float);
static __device__ __forceinline__ float exp2_native(float x) {
  return __ocml_native_exp2_f32(x);
}
#endif

// bf16 truncation pack: low ushort <- a, high ushort <- b (1x v_perm_b32).
static __device__ __forceinline__ unsigned int pack_trunc_f(float a, float b) {
  return __builtin_amdgcn_perm(__float_as_uint(b), __float_as_uint(a), 0x07060302);
}

// async global->LDS, 16B/lane: LDS dest = wave-uniform base + lane*16 (HW adds)
typedef const __attribute__((address_space(1))) unsigned int gu32;
typedef __attribute__((address_space(3))) unsigned int lu32;
static __device__ __forceinline__ void gload_lds16(const void* g, void* l) {
  __builtin_amdgcn_global_load_lds((gu32*)g, (lu32*)l, 16, 0, 0);
}

// ---------------------------------------------------------------------------
// proj: y = x(32768x64) * K^T(64x80) via MFMA 16x16x32. Block=256thr/4 waves.
// g-columns pre-scaled by log2(e) so attn can use native exp2 directly.
// h stored per 128-key tile as [c][136] bf16 (8-slot pad, garbage) with keys
// at PERMUTED position kpos = bitswap2<->3(key&127): attn's S^T C-layout ==
// PV A-layout with contiguous B-frags. (Stride 136 = 68 words == 4 mod 32:
// 8-lane b128 phases hit distinct banks -> 0 conflicts, measured R4/R5.)
// ---------------------------------------------------------------------------
__global__ __launch_bounds__(256) void proj_kernel(
    const float* __restrict__ x, const float* __restrict__ kf,
    const float* __restrict__ kg, const float* __restrict__ kh,
    unsigned short* __restrict__ f_b, unsigned short* __restrict__ g_b,
    unsigned short* __restrict__ h_p)
{
  __shared__ unsigned short Kt[80*72];
  const int t = threadIdx.x, blk = blockIdx.x;

  #pragma unroll
  for (int r = 0; r < 20; ++r) {
    int idx = r*256 + t;                 // 5120 = 80x64
    int o = idx >> 6, c = idx & 63;
    float v = (o < 8) ? kf[c*8 + o]
            : (o < 16) ? kg[c*8 + (o-8)] * LOG2E
            : kh[c*64 + (o-16)];
    Kt[o*72 + c] = (unsigned short)(__float_as_uint(v) >> 16);
  }
  __syncthreads();

  const int w = t >> 6, lane = t & 63, l15 = lane & 15, quad = lane >> 4;
  const int Rbase = blk*64 + w*16;
  const int R = Rbase + l15;

  bf16x8 af[2];
  #pragma unroll
  for (int kk = 0; kk < 2; ++kk) {
    const float* xp = x + (long)R*64 + kk*32 + quad*8;
    float4 v0 = *(const float4*)xp;
    float4 v1 = *(const float4*)(xp + 4);
    union { unsigned int u[4]; bf16x8 v; } p;
    p.u[0] = pack_trunc_f(v0.x, v0.y);
    p.u[1] = pack_trunc_f(v0.z, v0.w);
    p.u[2] = pack_trunc_f(v1.x, v1.y);
    p.u[3] = pack_trunc_f(v1.z, v1.w);
    af[kk] = p.v;
  }

  f32x4 acc[5];
  #pragma unroll
  for (int nt = 0; nt < 5; ++nt) { f32x4 z = {}; acc[nt] = z; }

  #pragma unroll
  for (int nt = 0; nt < 5; ++nt)
    #pragma unroll
    for (int kk = 0; kk < 2; ++kk) {
      bf16x8 bfv = *(const bf16x8*)&Kt[(nt*16 + l15)*72 + kk*32 + quad*8];
      acc[nt] = __builtin_amdgcn_mfma_f32_16x16x32_bf16(af[kk], bfv, acc[nt], 0, 0, 0);
    }

  const int bt = Rbase >> 12;
  const int kt = (Rbase >> 7) & 31;
  const int base = ((blk & 1) << 6) + (w << 4);
  // permuted store position: swap bits 2<->3 of (base + 4*quad + rr)
  const int pi = base + ((quad & 1) << 3) + (((quad >> 1) & 1) << 2);

  #pragma unroll
  for (int rr = 0; rr < 4; ++rr) {
    const int nq = (Rbase + quad*4 + rr) & 4095;
    unsigned short v = (unsigned short)(__float_as_uint(acc[0][rr]) >> 16);
    if (l15 < 8) f_b[((long)bt*4096 + nq)*8 + l15] = v;
    else         g_b[((long)bt*4096 + nq)*8 + (l15 - 8)] = v;
  }
  #pragma unroll
  for (int nt = 1; nt < 5; ++nt) {
    const int c = (nt - 1)*16 + l15;
    uint2 v;
    v.x = pack_trunc_f(acc[nt][0], acc[nt][1]);
    v.y = pack_trunc_f(acc[nt][2], acc[nt][3]);
    *(uint2*)(h_p + ((long)(bt*32 + kt)*64 + c)*136 + pi) = v;
  }
}

// ---------------------------------------------------------------------------
// attn: split-K flash attention (no-max softmax; |s| << 1 by construction).
// Grid (32 qtiles, 8 batch, 4 splits); block = 128 thr = 2 waves;
// wave = 64 queries in 2 q-groups sharing every LDS read (f + h B-frags).
// Double-buffered LDS staging via global_load_lds with ONE barrier per tile:
//   barrier (drains tile-t loads) -> issue tile-t+1 loads into other buffer
//   -> compute tile t.  The vmcnt(0) at the next barrier lands after a full
//   compute phase, so staging latency is fully hidden.
// Per 32-key sub-tile mt: 1 f-read feeds 2 S^T MFMAs (one per q-group,
// K=8 padded: g zeroed on lane-half a=1), native exp2, trunc-pack ->
// PV A-frags (C-reg order == A-slot order via the bit-swapped h storage),
// B-frags read once and reused by both q-groups.
// Partials: o (bf16) and l (f32) per split -> combine kernel.
// ---------------------------------------------------------------------------
__global__ __launch_bounds__(128, 2) void attn_kernel(
    const unsigned short* __restrict__ f_b, const unsigned short* __restrict__ g_b,
    const unsigned short* __restrict__ h_p, unsigned short* __restrict__ po,
    float* __restrict__ pl)
{
  // buf = h tile [64][136] (17408 B) then f tile [128][8] (2048 B)
  __shared__ unsigned short bufs[2][9728];

  const int t = threadIdx.x;
  const int w = t >> 6, lane = t & 63, l31 = lane & 31, a = lane >> 5;
  const int qb = blockIdx.x, b = blockIdx.y, sp = blockIdx.z;
  const int q0w = qb*128 + w*64;

  // g B-frags, one per q-group: n = q = l31, k = a*8+j ; real only at a=0
  bf16x8 gf[2];
  #pragma unroll
  for (int qg = 0; qg < 2; ++qg) {
    bf16x8 gv = *(const bf16x8*)(g_b + ((long)b*4096 + q0w + qg*32 + l31)*8);
    bf16x8 z = {};
    gf[qg] = (a == 0) ? gv : z;
  }

  f32x16 oacc[2][2];
  { f32x16 z = {}; oacc[0][0] = z; oacc[0][1] = z; oacc[1][0] = z; oacc[1][1] = z; }
  float l_run[2] = {0.f, 0.f};

  const char* hp_b = (const char*)h_p + (long)b*32*17408;
  const char* fb_b = (const char*)f_b + (long)b*4096*16;

  // stage tile (sp*8 + kti) into bufs[bi]
  auto stage = [&](int bi, int kt) {
    const char* hsrc = hp_b + (long)kt*17408;
    const char* fsrc = fb_b + (long)kt*2048;
    char* dst = (char*)&bufs[bi][0];
    #pragma unroll
    for (int i = 0; i < 8; ++i)
      gload_lds16(hsrc + i*2048 + w*1024 + lane*16, dst + i*2048 + w*1024);
    if (w == 0) {
      gload_lds16(hsrc + 16384 + lane*16, dst + 16384);
    } else {
      gload_lds16(fsrc + lane*16,        dst + 17408);
      gload_lds16(fsrc + 1024 + lane*16, dst + 17408 + 1024);
    }
  };

  stage(0, sp*8);

  for (int ktl = 0; ktl < 8; ++ktl) {
    __syncthreads();                     // drains tile-ktl loads; protects reuse
    if (ktl < 7) stage((ktl + 1) & 1, sp*8 + ktl + 1);

    const unsigned short* hts = &bufs[ktl & 1][0];
    const unsigned short* fts = &bufs[ktl & 1][8704];

    #pragma unroll
    for (int mt = 0; mt < 4; ++mt) {
      // S^T sub-tile: keys mt*32.. (storage order) x 64 queries (2 groups)
      bf16x8 afv = *(const bf16x8*)&fts[(mt*32 + l31)*8];
      f32x16 zz = {};
      f32x16 sc0 = __builtin_amdgcn_mfma_f32_32x32x16_bf16(afv, gf[0], zz, 0, 0, 0);
      f32x16 sc1 = __builtin_amdgcn_mfma_f32_32x32x16_bf16(afv, gf[1], zz, 0, 0, 0);

      float e0[16], e1[16];
      #pragma unroll
      for (int r = 0; r < 16; ++r) {
        e0[r] = exp2_native(sc0[r]);     // g pre-scaled by log2e
        e1[r] = exp2_native(sc1[r]);
        l_run[0] += e0[r];
        l_run[1] += e1[r];
      }

      #pragma unroll
      for (int half = 0; half < 2; ++half) {
        const int s = mt*2 + half;       // PV K-step: contraction k in [16s,16s+16)
        bf16x8 bh0 = *(const bf16x8*)&hts[(l31)*136      + s*16 + a*8];
        bf16x8 bh1 = *(const bf16x8*)&hts[(32 + l31)*136 + s*16 + a*8];
        union { unsigned int u[4]; bf16x8 v; } ap0, ap1;
        #pragma unroll
        for (int j = 0; j < 4; ++j) {
          ap0.u[j] = pack_trunc_f(e0[half*8 + 2*j], e0[half*8 + 2*j + 1]);
          ap1.u[j] = pack_trunc_f(e1[half*8 + 2*j], e1[half*8 + 2*j + 1]);
        }
        oacc[0][0] = __builtin_amdgcn_mfma_f32_32x32x16_bf16(ap0.v, bh0, oacc[0][0], 0, 0, 0);
        oacc[0][1] = __builtin_amdgcn_mfma_f32_32x32x16_bf16(ap0.v, bh1, oacc[0][1], 0, 0, 0);
        oacc[1][0] = __builtin_amdgcn_mfma_f32_32x32x16_bf16(ap1.v, bh0, oacc[1][0], 0, 0, 0);
        oacc[1][1] = __builtin_amdgcn_mfma_f32_32x32x16_bf16(ap1.v, bh1, oacc[1][1], 0, 0, 0);
      }
    }
  }

  const long sb = (long)sp*8 + b;
  #pragma unroll
  for (int qg = 0; qg < 2; ++qg) {
    float l = l_run[qg] + __shfl_xor(l_run[qg], 32);
    if (lane < 32) pl[(sb << 12) + q0w + qg*32 + l31] = l;
    // partial o: C col = c = nt*32+l31, row q = (r&3)+8*(r>>2)+4a
    unsigned short* pob = po + ((sb << 12) + q0w + qg*32)*64;
    #pragma unroll
    for (int nt = 0; nt < 2; ++nt)
      #pragma unroll
      for (int r = 0; r < 16; ++r) {
        const int q = (r & 3) + 8*(r >> 2) + 4*a;
        pob[(long)q*64 + nt*32 + l31] =
            (unsigned short)(__float_as_uint(oacc[qg][nt][r]) >> 16);
      }
  }
}

// ---------------------------------------------------------------------------
// combine: out = gamma * (sum_s po) / (sum_s pl) + x.  One thread = 8 channels.
// ---------------------------------------------------------------------------
__global__ __launch_bounds__(256) void combine_kernel(
    const float* __restrict__ x, const unsigned short* __restrict__ po,
    const float* __restrict__ pl, const float* __restrict__ gamma_p,
    float* __restrict__ out)
{
  const long tid = (long)blockIdx.x*256 + threadIdx.x;   // 262144
  const long bn = tid >> 3;
  const int c0 = (int)(tid & 7)*8;

  float l = 0.f;
  float o[8];
  #pragma unroll
  for (int i = 0; i < 8; ++i) o[i] = 0.f;
  #pragma unroll
  for (int s = 0; s < 4; ++s) {
    l += pl[(long)s*32768 + bn];
    uint4 v = *(const uint4*)(po + ((long)s*32768 + bn)*64 + c0);
    const unsigned short* pv = (const unsigned short*)&v;
    #pragma unroll
    for (int i = 0; i < 8; ++i)
      o[i] += __uint_as_float((unsigned int)pv[i] << 16);
  }
  const float scale = gamma_p[0] / l;
  const float* xp = x + bn*64 + c0;
  float4 x0 = *(const float4*)xp;
  float4 x1 = *(const float4*)(xp + 4);
  float4 r0, r1;
  r0.x = fmaf(scale, o[0], x0.x);
  r0.y = fmaf(scale, o[1], x0.y);
  r0.z = fmaf(scale, o[2], x0.z);
  r0.w = fmaf(scale, o[3], x0.w);
  r1.x = fmaf(scale, o[4], x1.x);
  r1.y = fmaf(scale, o[5], x1.y);
  r1.z = fmaf(scale, o[6], x1.z);
  r1.w = fmaf(scale, o[7], x1.w);
  float* op = out + bn*64 + c0;
  *(float4*)op = r0;
  *(float4*)(op + 4) = r1;
}

extern "C" void kernel_launch(void* const* d_in, const int* in_sizes, int n_in,
                              void* d_out, int out_size, void* d_ws, size_t ws_size,
                              hipStream_t stream) {
  const float* x  = (const float*)d_in[0];
  const float* kf = (const float*)d_in[1];
  const float* kg = (const float*)d_in[2];
  const float* kh = (const float*)d_in[3];
  const float* gamma = (const float*)d_in[4];
  float* out = (float*)d_out;

  char* ws = (char*)d_ws;
  unsigned short* h_p = (unsigned short*)ws;                  // 8*32*64*136*2 = 4,456,448
  unsigned short* f_b = (unsigned short*)(ws + 4456448);      // 524,288
  unsigned short* g_b = (unsigned short*)(ws + 4980736);      // 524,288
  unsigned short* po  = (unsigned short*)(ws + 5505024);      // 4*8*4096*64*2 = 16,777,216
  float*          pl  = (float*)(ws + 22282240);              // 4*8*4096*4 = 524,288

  proj_kernel<<<512, 256, 0, stream>>>(x, kf, kg, kh, f_b, g_b, h_p);
  attn_kernel<<<dim3(32, 8, 4), 128, 0, stream>>>(f_b, g_b, h_p, po, pl);
  combine_kernel<<<1024, 256, 0, stream>>>(x, po, pl, gamma, out);
}